// Round 2
// baseline (57.727 us; speedup 1.0000x reference)
//
#include <hip/hip_runtime.h>

#define B_ 4
#define N_ 64
#define H_ 512
#define W_ 512
#define MH 28
#define MW 28
#define TILE_ROWS 16

typedef float f32x4 __attribute__((ext_vector_type(4)));

// One fused kernel. Block = (bn, 16-row tile). 256 threads: 128/row-pair, 4 px/thread.
// Grid = 256 boxes * 32 tiles = 8192 blocks (32/CU nominal, ~8 resident).
__global__ __launch_bounds__(256) void fused_paste(const float* __restrict__ det,
                                                   const float* __restrict__ ins,
                                                   float* __restrict__ out) {
    int bid  = blockIdx.x;
    int bn   = bid >> 5;         // 32 tiles per box
    int tile = bid & 31;
    int t    = threadIdx.x;

    // ---- global max score -> thr (redundant per block; L2-broadcast reads) ----
    float m = det[t * 6 + 5];    // t indexes the 256 boxes
#pragma unroll
    for (int off = 1; off < 64; off <<= 1) m = fmaxf(m, __shfl_xor(m, off));
    __shared__ float wmax[4];
    if ((t & 63) == 0) wmax[t >> 6] = m;
    __syncthreads();
    float gmax = fmaxf(fmaxf(wmax[0], wmax[1]), fmaxf(wmax[2], wmax[3]));
    float thr  = (gmax > 50.0f) ? 50.0f : -100.0f;

    // ---- per-box params (uniform across block) ----
    const float* d6 = det + bn * 6;
    float cx = fmaxf(d6[0], 1.0f);
    float cy = fmaxf(d6[1], 1.0f);
    float w  = fmaxf(d6[2], 1.0f);
    float h  = fmaxf(d6[3], 1.0f);
    float sc = d6[5];
    int xmin = min(max((int)ceilf(cx - w * 0.5f), 0), W_);
    int xmax = min(max((int)ceilf(cx + w * 0.5f), 0), W_);
    int ymin = min(max((int)ceilf(cy - h * 0.5f), 0), H_);
    int ymax = min(max((int)ceilf(cy + h * 0.5f), 0), H_);
    float out_h = (float)(ymax - ymin);
    float out_w = (float)(xmax - xmin);
    float sy = (out_h > 1.0f) ? (float)(MH - 1) / fmaxf(out_h - 1.0f, 1.0f) : 0.0f;
    float sx = (out_w > 1.0f) ? (float)(MW - 1) / fmaxf(out_w - 1.0f, 1.0f) : 0.0f;
    bool valid = (sc >= thr);

    int x0   = (t & 127) << 2;   // pixel column base
    int lrow = t >> 7;           // 0/1 within row pair

    // ---- x-interp terms: row-invariant, hoisted out of the row loop ----
    int   xi0[4], xi1[4];
    float wxv[4];
    bool  okx[4];
#pragma unroll
    for (int j = 0; j < 4; ++j) {
        int xp = x0 + j;
        okx[j] = (xp >= xmin) && (xp < xmax);
        float src_x = fminf(fmaxf(((float)xp - (float)xmin) * sx, 0.0f), (float)(MW - 1));
        float xf = floorf(src_x);
        xi0[j] = (int)xf;
        xi1[j] = min(xi0[j] + 1, MW - 1);
        wxv[j] = src_x - xf;
    }

    const float* mk    = ins + (size_t)bn * (MH * MW);
    float*       obase = out + (size_t)bn * (H_ * W_) + x0;

#pragma unroll
    for (int p = 0; p < TILE_ROWS / 2; ++p) {
        int y = tile * TILE_ROWS + p * 2 + lrow;
        f32x4 r = (f32x4)0.0f;
        if (valid && y >= ymin && y < ymax) {
            float src_y = fminf(fmaxf(((float)y - (float)ymin) * sy, 0.0f), (float)(MH - 1));
            float yf = floorf(src_y);
            int   y0 = (int)yf;
            int   y1 = min(y0 + 1, MH - 1);
            float wy = src_y - yf;
            const float* m0 = mk + y0 * MW;
            const float* m1 = mk + y1 * MW;
#pragma unroll
            for (int j = 0; j < 4; ++j) {
                float v = 0.0f;
                if (okx[j]) {
                    float a0 = m0[xi0[j]], b0 = m1[xi0[j]];
                    float a1 = m0[xi1[j]], b1 = m1[xi1[j]];
                    float r0 = a0 * (1.0f - wy) + b0 * wy;   // rows first (ref order)
                    float r1 = a1 * (1.0f - wy) + b1 * wy;
                    v = r0 * (1.0f - wxv[j]) + r1 * wxv[j];
                }
                r[j] = v;
            }
        }
        __builtin_nontemporal_store(r, (f32x4*)(obase + (size_t)y * W_));
    }
}

extern "C" void kernel_launch(void* const* d_in, const int* in_sizes, int n_in,
                              void* d_out, int out_size, void* d_ws, size_t ws_size,
                              hipStream_t stream) {
    const float* det = (const float*)d_in[1];   // [B,N,6]
    const float* ins = (const float*)d_in[2];   // [B,N,MH,MW]
    float* out = (float*)d_out;                 // [B,N,H,W]

    fused_paste<<<B_ * N_ * (H_ / TILE_ROWS), 256, 0, stream>>>(det, ins, out);
}

// Round 3
// 42.431 us; speedup vs baseline: 1.3605x; 1.3605x over previous
//
#include <hip/hip_runtime.h>

#define B_ 4
#define N_ 64
#define H_ 512
#define W_ 512
#define MH 28
#define MW 28
#define TILE_ROWS 8

typedef float f32x4 __attribute__((ext_vector_type(4)));

// Fused kernel. Block = (bn, 8-row tile). Grid = 256 boxes * 64 tiles = 16384 blocks.
// 256 threads: 128 threads per row (4 px float4 each), 2 rows per iteration, 4 iters.
// Prologue is wave-local (no LDS, no barrier): each wave reduces all 256 scores.
__global__ __launch_bounds__(256) void fused_paste(const float* __restrict__ det,
                                                   const float* __restrict__ ins,
                                                   float* __restrict__ out) {
    int bid  = blockIdx.x;
    int bn   = bid >> 6;         // 64 tiles per box
    int tile = bid & 63;
    int t    = threadIdx.x;
    int lane = t & 63;

    // ---- global max score (wave-local reduce, no barrier) ----
    float m = fmaxf(fmaxf(det[lane * 6 + 5],        det[(lane + 64) * 6 + 5]),
                    fmaxf(det[(lane + 128) * 6 + 5], det[(lane + 192) * 6 + 5]));
#pragma unroll
    for (int off = 1; off < 64; off <<= 1) m = fmaxf(m, __shfl_xor(m, off));
    float thr = (m > 50.0f) ? 50.0f : -100.0f;

    // ---- per-box params (block-uniform -> scalar path) ----
    const float* d6 = det + bn * 6;
    float cx = fmaxf(d6[0], 1.0f);
    float cy = fmaxf(d6[1], 1.0f);
    float w  = fmaxf(d6[2], 1.0f);
    float h  = fmaxf(d6[3], 1.0f);
    float sc = d6[5];
    int xmin = min(max((int)ceilf(cx - w * 0.5f), 0), W_);
    int xmax = min(max((int)ceilf(cx + w * 0.5f), 0), W_);
    int ymin = min(max((int)ceilf(cy - h * 0.5f), 0), H_);
    int ymax = min(max((int)ceilf(cy + h * 0.5f), 0), H_);
    float out_h = (float)(ymax - ymin);
    float out_w = (float)(xmax - xmin);
    float sy = (out_h > 1.0f) ? (float)(MH - 1) / fmaxf(out_h - 1.0f, 1.0f) : 0.0f;
    float sx = (out_w > 1.0f) ? (float)(MW - 1) / fmaxf(out_w - 1.0f, 1.0f) : 0.0f;
    bool valid = (sc >= thr);

    int x0   = (t & 127) << 2;   // pixel column base
    int lrow = t >> 7;           // 0/1 within each row pair

    // ---- x-interp terms: row-invariant, hoisted ----
    int   xi0[4], xi1[4];
    float wxv[4];
    bool  okx[4];
#pragma unroll
    for (int j = 0; j < 4; ++j) {
        int xp = x0 + j;
        okx[j] = (xp >= xmin) && (xp < xmax);
        float src_x = fminf(fmaxf(((float)xp - (float)xmin) * sx, 0.0f), (float)(MW - 1));
        float xf = floorf(src_x);
        xi0[j] = (int)xf;
        xi1[j] = min(xi0[j] + 1, MW - 1);
        wxv[j] = src_x - xf;
    }

    const float* mk    = ins + (size_t)bn * (MH * MW);
    float*       obase = out + (size_t)bn * (H_ * W_) + x0;

#pragma unroll
    for (int p = 0; p < TILE_ROWS / 2; ++p) {
        int y = tile * TILE_ROWS + p * 2 + lrow;
        f32x4 r = (f32x4)0.0f;
        if (valid && y >= ymin && y < ymax) {
            float src_y = fminf(fmaxf(((float)y - (float)ymin) * sy, 0.0f), (float)(MH - 1));
            float yf = floorf(src_y);
            int   y0 = (int)yf;
            int   y1 = min(y0 + 1, MH - 1);
            float wy = src_y - yf;
            const float* m0 = mk + y0 * MW;
            const float* m1 = mk + y1 * MW;
#pragma unroll
            for (int j = 0; j < 4; ++j) {
                float v = 0.0f;
                if (okx[j]) {
                    float a0 = m0[xi0[j]], b0 = m1[xi0[j]];
                    float a1 = m0[xi1[j]], b1 = m1[xi1[j]];
                    float r0 = a0 * (1.0f - wy) + b0 * wy;   // rows first (ref order)
                    float r1 = a1 * (1.0f - wy) + b1 * wy;
                    v = r0 * (1.0f - wxv[j]) + r1 * wxv[j];
                }
                r[j] = v;
            }
        }
        *(f32x4*)(obase + (size_t)y * W_) = r;   // regular store (write path as R1/fill)
    }
}

extern "C" void kernel_launch(void* const* d_in, const int* in_sizes, int n_in,
                              void* d_out, int out_size, void* d_ws, size_t ws_size,
                              hipStream_t stream) {
    const float* det = (const float*)d_in[1];   // [B,N,6]
    const float* ins = (const float*)d_in[2];   // [B,N,MH,MW]
    float* out = (float*)d_out;                 // [B,N,H,W]

    fused_paste<<<B_ * N_ * (H_ / TILE_ROWS), 256, 0, stream>>>(det, ins, out);
}